// Round 10
// baseline (243.608 us; speedup 1.0000x reference)
//
#include <hip/hip_runtime.h>
#include <hip/hip_bf16.h>

// MLPDecoder: scores[e] = relu((h[src]*h[dst]) @ W1 + b1) @ W2 + b2
// E=300000, D=256. bf16 MFMA.
// R1-R5: see git history. R6 WIN: 64-col waves + lb(256,2): 64.2us.
// R7 ABLATION: staging-only = 2.26us/tile (fetch 3.35 TB/s); V0 =
// 3.46us/tile ~= 2.26+1.2 SERIAL: loads drain during compute -> queue
// empties -> fetch path de-saturates.
// R8 REGRESSION (70.2): GRID 1024 halved J, amortization loss.
// R9 REGRESSION (78.5): depth-2 REG prefetch: +32 VGPR -> 128 + mild
// spill (WRITE 2.7MB) + par-branch broke the schedule. Reg-prefetch
// dimension is EXHAUSTED.
// R10: global_load_lds staging (zero prefetch VGPRs). Stage RAW src+dst
// rows (2x16KB) at iter START via 8x gload_lds(16B)/thread; drain at
// iter END (__syncthreads) -> flight = full compute phase. Hadamard
// moves into A-frag read (ds_read src+dst, hmul2, MFMA) — same bf16 math.
// Linear LDS dest forced -> XOR-swizzle chunk on BOTH global-src and
// LDS-read sides (rule #21): gc = slot ^ (row&7); uniform 8 lanes/group.
// Pred: VGPR ~200, WRITE ~1.2MB, dur 64->~45-52us. Fail->revert R6.

#define E_EDGES 300000
#define DIM 256
#define MT 32                    // edges per block-iteration
#define NTILES (E_EDGES / MT)    // 9375
#define BLK 256                  // 4 waves; each wave owns 64 N-cols
#define GRID_MAIN 512            // 2 blocks/CU
#define MAXJ 19                  // ceil(9375/512)

typedef short bf16x8 __attribute__((ext_vector_type(8)));
typedef float f32x4 __attribute__((ext_vector_type(4)));

__device__ __forceinline__ ushort f2bf(float f) {
    union { float f; unsigned u; } v; v.f = f;
    unsigned r = v.u + 0x7FFFu + ((v.u >> 16) & 1u);  // RNE
    return (ushort)(r >> 16);
}

// async 16B global->LDS (DMA; dest = wave-uniform base + lane*16)
__device__ __forceinline__ void gl_lds16(const ushort* g, ushort* l) {
    __builtin_amdgcn_global_load_lds(
        (const __attribute__((address_space(1))) void*)g,
        (__attribute__((address_space(3))) void*)l, 16, 0, 0);
}

__device__ __forceinline__ bf16x8 hmul8(bf16x8 a, bf16x8 b) {
    union U { bf16x8 v; __hip_bfloat162 h[4]; } ua, ub, o;
    ua.v = a; ub.v = b;
#pragma unroll
    for (int q = 0; q < 4; ++q) o.h[q] = __hmul2(ua.h[q], ub.h[q]);
    return o.v;
}

// W1 fp32 [K=256][N=256] -> W1^T bf16 [N][K]
__global__ void prep_w1t(const float* __restrict__ w1, ushort* __restrict__ w1t) {
    int idx = blockIdx.x * 256 + threadIdx.x;
    int k = idx >> 8, n = idx & 255;
    w1t[n * 256 + k] = f2bf(w1[k * 256 + n]);
}

// h fp32 -> bf16
__global__ void prep_hbf(const float* __restrict__ h, ushort* __restrict__ hbf) {
    int i = blockIdx.x * 256 + threadIdx.x;
    const float4* src = (const float4*)h + (size_t)i * 2;
    float4 a = src[0], b = src[1];
    union { ushort s[8]; uint4 v; } o;
    o.s[0] = f2bf(a.x); o.s[1] = f2bf(a.y); o.s[2] = f2bf(a.z); o.s[3] = f2bf(a.w);
    o.s[4] = f2bf(b.x); o.s[5] = f2bf(b.y); o.s[6] = f2bf(b.z); o.s[7] = f2bf(b.w);
    ((uint4*)hbf)[i] = o.v;
}

__global__ __launch_bounds__(BLK, 2)
void decoder(const ushort* __restrict__ hbf, const int2* __restrict__ edges,
             const ushort* __restrict__ w1t, const float* __restrict__ b1,
             const float* __restrict__ w2, const float* __restrict__ b2p,
             float* __restrict__ out) {
    // sbuf[par][src|dst][row][256] — LINEAR rows (gload_lds requirement);
    // swizzle lives in the source-chunk permutation, not the layout.
    __shared__ ushort sbuf[2][2][MT][256];  // 64 KB
    __shared__ float part[2][4][MT];        // 1 KB
    __shared__ int2 eld[MAXJ * MT];         // 4.9 KB

    const int t = threadIdx.x;
    const int w = t >> 6, lane = t & 63, quad = lane >> 4, l15 = lane & 15;
    const int bx = blockIdx.x, gdim = gridDim.x;
    const int J = (NTILES - bx + gdim - 1) / gdim;   // 18 or 19 tiles

    bf16x8 Bf[4][8];   // wave w owns N cols [64w, 64w+64)
#pragma unroll
    for (int nt = 0; nt < 4; ++nt) {
        int n = w * 64 + nt * 16 + l15;
#pragma unroll
        for (int ks = 0; ks < 8; ++ks)
            Bf[nt][ks] = *(const bf16x8*)(w1t + n * 256 + ks * 32 + quad * 8);
    }
    float b1v[4], w2v[4];
#pragma unroll
    for (int nt = 0; nt < 4; ++nt) {
        int n = w * 64 + nt * 16 + l15;
        b1v[nt] = b1[n];
        w2v[nt] = w2[n];
    }
    const float b2v = b2p[0];

    for (int idx = t; idx < J * MT; idx += BLK)
        eld[idx] = edges[(size_t)(bx + (idx >> 5) * gdim) * MT + (idx & 31)];
    __syncthreads();

    const int rbase = t >> 5;   // 0..7: row-slot (wave*2 + lanehalf)
    const int slot  = t & 31;   // dest 16B chunk within 512B row

    // stage tile j into sbuf[buf]: 8 gload_lds per thread, no VGPR staging.
    // LDS[row][slot] holds global chunk (slot ^ (row&7))  [XOR involution]
    auto stage = [&](int j, int buf) {
#pragma unroll
        for (int r = 0; r < 4; ++r) {
            int row = r * 8 + rbase;
            int2 ed = eld[j * MT + row];
            int gc = slot ^ (row & 7);
            gl_lds16(hbf + (size_t)ed.x * DIM + gc * 8, &sbuf[buf][0][row][slot * 8]);
            gl_lds16(hbf + (size_t)ed.y * DIM + gc * 8, &sbuf[buf][1][row][slot * 8]);
        }
    };
    auto finalize = [&](int j, int par) {
        if (t < MT) {
            float s = b2v;
#pragma unroll
            for (int ww = 0; ww < 4; ++ww) s += part[par][ww][t];
            out[(size_t)(bx + j * gdim) * MT + t] = s;
        }
    };

    // prologue: stage tile 0, drain, barrier
    stage(0, 0);
    __syncthreads();

    for (int j = 0; j < J; ++j) {
        const int par = j & 1;

        // issue next tile's DMA FIRST (T14): lands during compute below
        if (j + 1 < J) stage(j + 1, par ^ 1);
        if (j > 0) finalize(j - 1, par ^ 1);

        // ---- compute tile j from sbuf[par]: hadamard fused into A-frag ----
        f32x4 acc[2][4];
#pragma unroll
        for (int ms = 0; ms < 2; ++ms)
#pragma unroll
            for (int nt = 0; nt < 4; ++nt)
                acc[ms][nt] = (f32x4){0.f, 0.f, 0.f, 0.f};
        const ushort* sb = &sbuf[par][0][0][0];
        const ushort* db = &sbuf[par][1][0][0];
#pragma unroll
        for (int ks = 0; ks < 8; ++ks) {
            int c = ks * 4 + quad;                       // 16B chunk index
            int off0 = l15 * 256 + ((c ^ (l15 & 7)) * 8);          // row l15
            int off1 = (16 + l15) * 256 + ((c ^ (l15 & 7)) * 8);   // row 16+l15
            bf16x8 a0 = hmul8(*(const bf16x8*)(sb + off0), *(const bf16x8*)(db + off0));
            bf16x8 a1 = hmul8(*(const bf16x8*)(sb + off1), *(const bf16x8*)(db + off1));
#pragma unroll
            for (int nt = 0; nt < 4; ++nt) {
                acc[0][nt] = __builtin_amdgcn_mfma_f32_16x16x32_bf16(a0, Bf[nt][ks], acc[0][nt], 0, 0, 0);
                acc[1][nt] = __builtin_amdgcn_mfma_f32_16x16x32_bf16(a1, Bf[nt][ks], acc[1][nt], 0, 0, 0);
            }
        }
        // epilogue: relu(hid+b1).w2, butterfly over 16 n-lanes
        float red[2][4];
#pragma unroll
        for (int ms = 0; ms < 2; ++ms)
#pragma unroll
            for (int r = 0; r < 4; ++r) {
                float s = 0.f;
#pragma unroll
                for (int nt = 0; nt < 4; ++nt)
                    s += fmaxf(acc[ms][nt][r] + b1v[nt], 0.f) * w2v[nt];
                red[ms][r] = s;
            }
#pragma unroll
        for (int mask = 1; mask <= 8; mask <<= 1)
#pragma unroll
            for (int ms = 0; ms < 2; ++ms)
#pragma unroll
                for (int r = 0; r < 4; ++r)
                    red[ms][r] += __shfl_xor(red[ms][r], mask);
        if (l15 == 0)
#pragma unroll
            for (int ms = 0; ms < 2; ++ms)
#pragma unroll
                for (int r = 0; r < 4; ++r)
                    part[par][w][ms * 16 + quad * 4 + r] = red[ms][r];

        // drain this iter's DMA (had full compute phase to land) + barrier
        __syncthreads();
    }

    finalize(J - 1, (J - 1) & 1);
}

// fp32-gather fallback (only if ws too small for hbf; not expected to run)
__global__ __launch_bounds__(512, 4)
void decoder_f32(const float* __restrict__ h, const int2* __restrict__ edges,
                 const ushort* __restrict__ w1t, const float* __restrict__ b1,
                 const float* __restrict__ w2, const float* __restrict__ b2p,
                 float* __restrict__ out) {
    __shared__ ushort xlds[MT][264];
    __shared__ float part[8][MT];
    const int t = threadIdx.x;
    const int w = t >> 6, lane = t & 63, quad = lane >> 4, l15 = lane & 15;
    bf16x8 Bf[2][8];
#pragma unroll
    for (int nt = 0; nt < 2; ++nt)
#pragma unroll
        for (int ks = 0; ks < 8; ++ks)
            Bf[nt][ks] = *(const bf16x8*)(w1t + (w * 32 + nt * 16 + l15) * 256 + ks * 32 + quad * 8);
    float b1v[2], w2v[2];
#pragma unroll
    for (int nt = 0; nt < 2; ++nt) {
        b1v[nt] = b1[w * 32 + nt * 16 + l15];
        w2v[nt] = w2[w * 32 + nt * 16 + l15];
    }
    const float b2v = b2p[0];
    const int sm = t >> 4, sc = t & 15;
    for (int mb = blockIdx.x; mb < NTILES; mb += gridDim.x) {
        int2 ed = edges[mb * MT + sm];
        const float4* ps = (const float4*)(h + (size_t)ed.x * DIM) + sc * 4;
        const float4* pd = (const float4*)(h + (size_t)ed.y * DIM) + sc * 4;
        union { ushort s[16]; uint4 v[2]; } o;
#pragma unroll
        for (int jj = 0; jj < 4; ++jj) {
            float4 a = ps[jj], b = pd[jj];
            o.s[4 * jj + 0] = f2bf(a.x * b.x); o.s[4 * jj + 1] = f2bf(a.y * b.y);
            o.s[4 * jj + 2] = f2bf(a.z * b.z); o.s[4 * jj + 3] = f2bf(a.w * b.w);
        }
        uint4* dst = (uint4*)&xlds[sm][sc * 16];
        dst[0] = o.v[0]; dst[1] = o.v[1];
        __syncthreads();
        f32x4 acc[2][2];
#pragma unroll
        for (int ms = 0; ms < 2; ++ms)
#pragma unroll
            for (int nt = 0; nt < 2; ++nt) acc[ms][nt] = (f32x4){0.f,0.f,0.f,0.f};
#pragma unroll
        for (int ks = 0; ks < 8; ++ks) {
            int kb = ks * 32 + quad * 8;
            bf16x8 a0 = *(const bf16x8*)&xlds[l15][kb];
            bf16x8 a1 = *(const bf16x8*)&xlds[16 + l15][kb];
#pragma unroll
            for (int nt = 0; nt < 2; ++nt) {
                acc[0][nt] = __builtin_amdgcn_mfma_f32_16x16x32_bf16(a0, Bf[nt][ks], acc[0][nt], 0, 0, 0);
                acc[1][nt] = __builtin_amdgcn_mfma_f32_16x16x32_bf16(a1, Bf[nt][ks], acc[1][nt], 0, 0, 0);
            }
        }
        float red[2][4];
#pragma unroll
        for (int ms = 0; ms < 2; ++ms)
#pragma unroll
            for (int r = 0; r < 4; ++r) {
                float s = 0.f;
#pragma unroll
                for (int nt = 0; nt < 2; ++nt)
                    s += fmaxf(acc[ms][nt][r] + b1v[nt], 0.f) * w2v[nt];
                red[ms][r] = s;
            }
#pragma unroll
        for (int mask = 1; mask <= 8; mask <<= 1)
#pragma unroll
            for (int ms = 0; ms < 2; ++ms)
#pragma unroll
                for (int r = 0; r < 4; ++r)
                    red[ms][r] += __shfl_xor(red[ms][r], mask);
        if (l15 == 0)
#pragma unroll
            for (int ms = 0; ms < 2; ++ms)
#pragma unroll
                for (int r = 0; r < 4; ++r)
                    part[w][ms * 16 + quad * 4 + r] = red[ms][r];
        __syncthreads();
        if (t < MT) {
            float s = b2v;
#pragma unroll
            for (int ww = 0; ww < 8; ++ww) s += part[ww][t];
            out[mb * MT + t] = s;
        }
    }
}

extern "C" void kernel_launch(void* const* d_in, const int* in_sizes, int n_in,
                              void* d_out, int out_size, void* d_ws, size_t ws_size,
                              hipStream_t stream) {
    const float* h     = (const float*)d_in[0];
    const int2*  edges = (const int2*)d_in[1];
    const float* W1    = (const float*)d_in[2];
    const float* b1    = (const float*)d_in[3];
    const float* W2    = (const float*)d_in[4];
    const float* b2    = (const float*)d_in[5];
    float* out = (float*)d_out;

    ushort* w1t = (ushort*)d_ws;                     // 128 KB
    ushort* hbf = (ushort*)((char*)d_ws + 131072);   // 51.2 MB

    prep_w1t<<<256, 256, 0, stream>>>(W1, w1t);
    if (ws_size >= 131072 + (size_t)25600000 * 2) {
        prep_hbf<<<12500, 256, 0, stream>>>(h, hbf);
        decoder<<<GRID_MAIN, BLK, 0, stream>>>(hbf, edges, w1t, b1, W2, b2, out);
    } else {
        decoder_f32<<<512, 512, 0, stream>>>(h, edges, w1t, b1, W2, b2, out);
    }
}

// Round 11
// 222.270 us; speedup vs baseline: 1.0960x; 1.0960x over previous
//
#include <hip/hip_runtime.h>
#include <hip/hip_bf16.h>

// MLPDecoder: scores[e] = relu((h[src]*h[dst]) @ W1 + b1) @ W2 + b2
// E=300000, D=256. bf16 MFMA.
// R1-R5: see git history. R6 WIN: 64-col waves + lb(256,2): 64.2us.
// R7 ABLATION: staging-only = 2.26us/tile (fetch 3.35 TB/s); V0 3.46.
// R8 REGRESSION (70.2): GRID 1024 halved J, amortization loss.
// R9 REGRESSION (78.5): depth-2 reg prefetch -> 128 VGPR + mild spill.
// R10 REGRESSION (92.0): gload_lds + hadamard fused into A-read = 4x
// duplicated hadamard across waves (VALUBusy 26->46%) + 2x LDS reads.
// Lesson: hadamard must happen ONCE (in regs at staging), not per-wave.
// R11: exact R6 champion + two zero-register tweaks to raise gather
// ISSUE RATE (v1 sustains 3.35TB/s with back-to-back issue; V0's burst
// at iter-end leaves the pipe idle during compute):
//  (1) had+issue moved BEFORE MFMA (regs were filled a full iter ago ->
//      no stall; refill goes out ~1.5us earlier each iter).
//  (2) s_setprio(1) around MFMA cluster (T5; 2 independent blocks/CU
//      give phase diversity, unlike lockstep-GEMM null).
// Pred: VGPR ~120, WRITE ~1.17MB (spill=abort), dur 64.2 -> 58-63us.
// If >=63.5 (neutral/worse): R6 structure is at ceiling; revert & stop.

#define E_EDGES 300000
#define DIM 256
#define MT 32                    // edges per block-iteration
#define NTILES (E_EDGES / MT)    // 9375
#define BLK 256                  // 4 waves; each wave owns 64 N-cols
#define GRID_MAIN 512            // 2 blocks/CU
#define MAXJ 19                  // ceil(9375/512)

typedef short bf16x8 __attribute__((ext_vector_type(8)));
typedef float f32x4 __attribute__((ext_vector_type(4)));

__device__ __forceinline__ ushort f2bf(float f) {
    union { float f; unsigned u; } v; v.f = f;
    unsigned r = v.u + 0x7FFFu + ((v.u >> 16) & 1u);  // RNE
    return (ushort)(r >> 16);
}

// Barrier that does NOT drain vmcnt (LDS producers covered by lgkmcnt(0)).
__device__ __forceinline__ void barrier_lgkm() {
    asm volatile("s_waitcnt lgkmcnt(0)" ::: "memory");
    asm volatile("s_barrier" ::: "memory");
}

// W1 fp32 [K=256][N=256] -> W1^T bf16 [N][K]
__global__ void prep_w1t(const float* __restrict__ w1, ushort* __restrict__ w1t) {
    int idx = blockIdx.x * 256 + threadIdx.x;
    int k = idx >> 8, n = idx & 255;
    w1t[n * 256 + k] = f2bf(w1[k * 256 + n]);
}

// h fp32 -> bf16
__global__ void prep_hbf(const float* __restrict__ h, ushort* __restrict__ hbf) {
    int i = blockIdx.x * 256 + threadIdx.x;
    const float4* src = (const float4*)h + (size_t)i * 2;
    float4 a = src[0], b = src[1];
    union { ushort s[8]; uint4 v; } o;
    o.s[0] = f2bf(a.x); o.s[1] = f2bf(a.y); o.s[2] = f2bf(a.z); o.s[3] = f2bf(a.w);
    o.s[4] = f2bf(b.x); o.s[5] = f2bf(b.y); o.s[6] = f2bf(b.z); o.s[7] = f2bf(b.w);
    ((uint4*)hbf)[i] = o.v;
}

__global__ __launch_bounds__(BLK, 2)
void decoder(const ushort* __restrict__ hbf, const int2* __restrict__ edges,
             const ushort* __restrict__ w1t, const float* __restrict__ b1,
             const float* __restrict__ w2, const float* __restrict__ b2p,
             float* __restrict__ out) {
    // stride 264: bank spread for b128 ops; double-buffered
    __shared__ ushort xlds[2][MT][264];   // 33.8 KB
    __shared__ float part[2][4][MT];      // 1 KB
    __shared__ int2 eld[MAXJ * MT];       // 4.9 KB

    const int t = threadIdx.x;
    const int w = t >> 6, lane = t & 63, quad = lane >> 4, l15 = lane & 15;
    const int bx = blockIdx.x, gdim = gridDim.x;
    const int J = (NTILES - bx + gdim - 1) / gdim;   // 18 or 19 tiles

    bf16x8 Bf[4][8];   // wave w owns N cols [64w, 64w+64)
#pragma unroll
    for (int nt = 0; nt < 4; ++nt) {
        int n = w * 64 + nt * 16 + l15;
#pragma unroll
        for (int ks = 0; ks < 8; ++ks)
            Bf[nt][ks] = *(const bf16x8*)(w1t + n * 256 + ks * 32 + quad * 8);
    }
    float b1v[4], w2v[4];
#pragma unroll
    for (int nt = 0; nt < 4; ++nt) {
        int n = w * 64 + nt * 16 + l15;
        b1v[nt] = b1[n];
        w2v[nt] = w2[n];
    }
    const float b2v = b2p[0];

    for (int idx = t; idx < J * MT; idx += BLK)
        eld[idx] = edges[(size_t)(bx + (idx >> 5) * gdim) * MT + (idx & 31)];
    __syncthreads();

    const int sm = t >> 3;     // edge row in tile 0..31
    const int sc = t & 7;      // 64B chunk in row

    // single prefetch set; plain named regs (no spill risk).
    uint4 s0, s1, s2, s3, d0, d1, d2, d3;

    auto issue = [&](int j) {
        int2 ed = eld[j * MT + sm];
        const uint4* ps = (const uint4*)(hbf + (size_t)ed.x * DIM) + sc * 4;
        const uint4* pd = (const uint4*)(hbf + (size_t)ed.y * DIM) + sc * 4;
        s0 = ps[0]; s1 = ps[1]; s2 = ps[2]; s3 = ps[3];
        d0 = pd[0]; d1 = pd[1]; d2 = pd[2]; d3 = pd[3];
    };
    auto mul8 = [](uint4 a, uint4 b) -> uint4 {
        union U { uint4 v; __hip_bfloat162 h[4]; } ua, ub, o;
        ua.v = a; ub.v = b;
#pragma unroll
        for (int q = 0; q < 4; ++q) o.h[q] = __hmul2(ua.h[q], ub.h[q]);
        return o.v;
    };
    auto had = [&](int buf) {
        uint4* dst = (uint4*)&xlds[buf][sm][sc * 32];
        dst[0] = mul8(s0, d0);
        dst[1] = mul8(s1, d1);
        dst[2] = mul8(s2, d2);
        dst[3] = mul8(s3, d3);
    };
    auto finalize = [&](int j, int par) {
        if (t < MT) {
            float s = b2v;
#pragma unroll
            for (int ww = 0; ww < 4; ++ww) s += part[par][ww][t];
            out[(size_t)(bx + j * gdim) * MT + t] = s;
        }
    };

    // prologue
    issue(0);
    had(0);                   // xlds[0] <- tile 0 (visible after first barrier)
    if (J > 1) issue(1);

    for (int j = 0; j < J; ++j) {
        const int par = j & 1;
        barrier_lgkm();                   // does NOT drain vmcnt
        if (j > 0) finalize(j - 1, par ^ 1);

        // ---- EARLY staging (R11): regs filled a full iter ago -> no stall;
        // refill goes out before MFMA so gathers fly during compute.
        if (j + 1 < J) had(par ^ 1);      // xlds[par^1] <- tile j+1
        if (j + 2 < J) issue(j + 2);      // in flight across MFMA + barrier

        // ---- MFMA on tile j from xlds[par] ----
        __builtin_amdgcn_s_setprio(1);    // T5: favor MFMA wave on CU sched
        f32x4 acc[2][4];
#pragma unroll
        for (int ms = 0; ms < 2; ++ms)
#pragma unroll
            for (int nt = 0; nt < 4; ++nt)
                acc[ms][nt] = (f32x4){0.f, 0.f, 0.f, 0.f};
        const ushort* xb = &xlds[par][0][0];
#pragma unroll
        for (int ks = 0; ks < 8; ++ks) {
            int kb = ks * 32 + quad * 8;
            bf16x8 a0 = *(const bf16x8*)(xb + l15 * 264 + kb);
            bf16x8 a1 = *(const bf16x8*)(xb + (16 + l15) * 264 + kb);
#pragma unroll
            for (int nt = 0; nt < 4; ++nt) {
                acc[0][nt] = __builtin_amdgcn_mfma_f32_16x16x32_bf16(a0, Bf[nt][ks], acc[0][nt], 0, 0, 0);
                acc[1][nt] = __builtin_amdgcn_mfma_f32_16x16x32_bf16(a1, Bf[nt][ks], acc[1][nt], 0, 0, 0);
            }
        }
        __builtin_amdgcn_s_setprio(0);

        // epilogue: relu(hid+b1).w2, butterfly over 16 n-lanes
        float red[2][4];
#pragma unroll
        for (int ms = 0; ms < 2; ++ms)
#pragma unroll
            for (int r = 0; r < 4; ++r) {
                float s = 0.f;
#pragma unroll
                for (int nt = 0; nt < 4; ++nt)
                    s += fmaxf(acc[ms][nt][r] + b1v[nt], 0.f) * w2v[nt];
                red[ms][r] = s;
            }
#pragma unroll
        for (int mask = 1; mask <= 8; mask <<= 1)
#pragma unroll
            for (int ms = 0; ms < 2; ++ms)
#pragma unroll
                for (int r = 0; r < 4; ++r)
                    red[ms][r] += __shfl_xor(red[ms][r], mask);
        if (l15 == 0)
#pragma unroll
            for (int ms = 0; ms < 2; ++ms)
#pragma unroll
                for (int r = 0; r < 4; ++r)
                    part[par][w][ms * 16 + quad * 4 + r] = red[ms][r];
    }

    __syncthreads();
    finalize(J - 1, (J - 1) & 1);
}

// fp32-gather fallback (only if ws too small for hbf; not expected to run)
__global__ __launch_bounds__(512, 4)
void decoder_f32(const float* __restrict__ h, const int2* __restrict__ edges,
                 const ushort* __restrict__ w1t, const float* __restrict__ b1,
                 const float* __restrict__ w2, const float* __restrict__ b2p,
                 float* __restrict__ out) {
    __shared__ ushort xlds[MT][264];
    __shared__ float part[8][MT];
    const int t = threadIdx.x;
    const int w = t >> 6, lane = t & 63, quad = lane >> 4, l15 = lane & 15;
    bf16x8 Bf[2][8];
#pragma unroll
    for (int nt = 0; nt < 2; ++nt)
#pragma unroll
        for (int ks = 0; ks < 8; ++ks)
            Bf[nt][ks] = *(const bf16x8*)(w1t + (w * 32 + nt * 16 + l15) * 256 + ks * 32 + quad * 8);
    float b1v[2], w2v[2];
#pragma unroll
    for (int nt = 0; nt < 2; ++nt) {
        b1v[nt] = b1[w * 32 + nt * 16 + l15];
        w2v[nt] = w2[w * 32 + nt * 16 + l15];
    }
    const float b2v = b2p[0];
    const int sm = t >> 4, sc = t & 15;
    for (int mb = blockIdx.x; mb < NTILES; mb += gridDim.x) {
        int2 ed = edges[mb * MT + sm];
        const float4* ps = (const float4*)(h + (size_t)ed.x * DIM) + sc * 4;
        const float4* pd = (const float4*)(h + (size_t)ed.y * DIM) + sc * 4;
        union { ushort s[16]; uint4 v[2]; } o;
#pragma unroll
        for (int jj = 0; jj < 4; ++jj) {
            float4 a = ps[jj], b = pd[jj];
            o.s[4 * jj + 0] = f2bf(a.x * b.x); o.s[4 * jj + 1] = f2bf(a.y * b.y);
            o.s[4 * jj + 2] = f2bf(a.z * b.z); o.s[4 * jj + 3] = f2bf(a.w * b.w);
        }
        uint4* dst = (uint4*)&xlds[sm][sc * 16];
        dst[0] = o.v[0]; dst[1] = o.v[1];
        __syncthreads();
        f32x4 acc[2][2];
#pragma unroll
        for (int ms = 0; ms < 2; ++ms)
#pragma unroll
            for (int nt = 0; nt < 2; ++nt) acc[ms][nt] = (f32x4){0.f,0.f,0.f,0.f};
#pragma unroll
        for (int ks = 0; ks < 8; ++ks) {
            int kb = ks * 32 + quad * 8;
            bf16x8 a0 = *(const bf16x8*)&xlds[l15][kb];
            bf16x8 a1 = *(const bf16x8*)&xlds[16 + l15][kb];
#pragma unroll
            for (int nt = 0; nt < 2; ++nt) {
                acc[0][nt] = __builtin_amdgcn_mfma_f32_16x16x32_bf16(a0, Bf[nt][ks], acc[0][nt], 0, 0, 0);
                acc[1][nt] = __builtin_amdgcn_mfma_f32_16x16x32_bf16(a1, Bf[nt][ks], acc[1][nt], 0, 0, 0);
            }
        }
        float red[2][4];
#pragma unroll
        for (int ms = 0; ms < 2; ++ms)
#pragma unroll
            for (int r = 0; r < 4; ++r) {
                float s = 0.f;
#pragma unroll
                for (int nt = 0; nt < 2; ++nt)
                    s += fmaxf(acc[ms][nt][r] + b1v[nt], 0.f) * w2v[nt];
                red[ms][r] = s;
            }
#pragma unroll
        for (int mask = 1; mask <= 8; mask <<= 1)
#pragma unroll
            for (int ms = 0; ms < 2; ++ms)
#pragma unroll
                for (int r = 0; r < 4; ++r)
                    red[ms][r] += __shfl_xor(red[ms][r], mask);
        if (l15 == 0)
#pragma unroll
            for (int ms = 0; ms < 2; ++ms)
#pragma unroll
                for (int r = 0; r < 4; ++r)
                    part[w][ms * 16 + quad * 4 + r] = red[ms][r];
        __syncthreads();
        if (t < MT) {
            float s = b2v;
#pragma unroll
            for (int ww = 0; ww < 8; ++ww) s += part[ww][t];
            out[mb * MT + t] = s;
        }
    }
}

extern "C" void kernel_launch(void* const* d_in, const int* in_sizes, int n_in,
                              void* d_out, int out_size, void* d_ws, size_t ws_size,
                              hipStream_t stream) {
    const float* h     = (const float*)d_in[0];
    const int2*  edges = (const int2*)d_in[1];
    const float* W1    = (const float*)d_in[2];
    const float* b1    = (const float*)d_in[3];
    const float* W2    = (const float*)d_in[4];
    const float* b2    = (const float*)d_in[5];
    float* out = (float*)d_out;

    ushort* w1t = (ushort*)d_ws;                     // 128 KB
    ushort* hbf = (ushort*)((char*)d_ws + 131072);   // 51.2 MB

    prep_w1t<<<256, 256, 0, stream>>>(W1, w1t);
    if (ws_size >= 131072 + (size_t)25600000 * 2) {
        prep_hbf<<<12500, 256, 0, stream>>>(h, hbf);
        decoder<<<GRID_MAIN, BLK, 0, stream>>>(hbf, edges, w1t, b1, W2, b2, out);
    } else {
        decoder_f32<<<512, 512, 0, stream>>>(h, edges, w1t, b1, W2, b2, out);
    }
}

// Round 12
// 219.528 us; speedup vs baseline: 1.1097x; 1.0125x over previous
//
#include <hip/hip_runtime.h>
#include <hip/hip_bf16.h>

// MLPDecoder: scores[e] = relu((h[src]*h[dst]) @ W1 + b1) @ W2 + b2
// E=300000, D=256. bf16 MFMA. CHAMPION = R6 (64.2us decoder, 220.8 total).
// Session ledger:
// R1 grid bump: NEUTRAL. R2 lb(512,8): VGPR clamp->spill FAILED.
// R3 GRID 1024 + lb(512,4): NEUTRAL (occupancy not the lever).
// R4 lgkm-only barrier + MFMA-first: NEUTRAL (kept: enables vmcnt-cross).
// R5 64-col + lb(256,4): clamp->spill FAILED.
// R6 64-col + lb(256,2): WIN 77.7 -> 64.2us. VGPR 120, no spill.
// R7 ABLATION: staging-only = 41.4us (fetch path 3.35 TB/s saturated);
//    MFMA adds <21us. Structure is staging-dominated.
// R8 GRID 1024: REGRESSION 70.2 (amortization loss, J halved).
// R9 depth-2 reg prefetch: REGRESSION 78.5 (128 VGPR + mild spill).
// R10 gload_lds + fused hadamard: REGRESSION 92.0 (4x duplicated
//    hadamard across waves, VALUBusy 46%).
// R11 early-issue + setprio: 65.7 (issue-order null; setprio -1.5us —
//    lockstep waves, nothing to arbitrate).
// VERDICT: residual 64.2-41.4 = serial LDS/VALU/epilogue in the same
// waves that staple the gather stream. All cheap exits measured shut;
// remaining exit (producer/consumer wave specialization) is the
// restructure class that regressed 3x. Locking champion.

#define E_EDGES 300000
#define DIM 256
#define MT 32                    // edges per block-iteration
#define NTILES (E_EDGES / MT)    // 9375
#define BLK 256                  // 4 waves; each wave owns 64 N-cols
#define GRID_MAIN 512            // 2 blocks/CU
#define MAXJ 19                  // ceil(9375/512)

typedef short bf16x8 __attribute__((ext_vector_type(8)));
typedef float f32x4 __attribute__((ext_vector_type(4)));

__device__ __forceinline__ ushort f2bf(float f) {
    union { float f; unsigned u; } v; v.f = f;
    unsigned r = v.u + 0x7FFFu + ((v.u >> 16) & 1u);  // RNE
    return (ushort)(r >> 16);
}

// Barrier that does NOT drain vmcnt (LDS producers covered by lgkmcnt(0)).
__device__ __forceinline__ void barrier_lgkm() {
    asm volatile("s_waitcnt lgkmcnt(0)" ::: "memory");
    asm volatile("s_barrier" ::: "memory");
}

// W1 fp32 [K=256][N=256] -> W1^T bf16 [N][K]
__global__ void prep_w1t(const float* __restrict__ w1, ushort* __restrict__ w1t) {
    int idx = blockIdx.x * 256 + threadIdx.x;
    int k = idx >> 8, n = idx & 255;
    w1t[n * 256 + k] = f2bf(w1[k * 256 + n]);
}

// h fp32 -> bf16
__global__ void prep_hbf(const float* __restrict__ h, ushort* __restrict__ hbf) {
    int i = blockIdx.x * 256 + threadIdx.x;
    const float4* src = (const float4*)h + (size_t)i * 2;
    float4 a = src[0], b = src[1];
    union { ushort s[8]; uint4 v; } o;
    o.s[0] = f2bf(a.x); o.s[1] = f2bf(a.y); o.s[2] = f2bf(a.z); o.s[3] = f2bf(a.w);
    o.s[4] = f2bf(b.x); o.s[5] = f2bf(b.y); o.s[6] = f2bf(b.z); o.s[7] = f2bf(b.w);
    ((uint4*)hbf)[i] = o.v;
}

__global__ __launch_bounds__(BLK, 2)
void decoder(const ushort* __restrict__ hbf, const int2* __restrict__ edges,
             const ushort* __restrict__ w1t, const float* __restrict__ b1,
             const float* __restrict__ w2, const float* __restrict__ b2p,
             float* __restrict__ out) {
    // stride 264: bank spread for b128 ops; double-buffered
    __shared__ ushort xlds[2][MT][264];   // 33.8 KB
    __shared__ float part[2][4][MT];      // 1 KB
    __shared__ int2 eld[MAXJ * MT];       // 4.9 KB

    const int t = threadIdx.x;
    const int w = t >> 6, lane = t & 63, quad = lane >> 4, l15 = lane & 15;
    const int bx = blockIdx.x, gdim = gridDim.x;
    const int J = (NTILES - bx + gdim - 1) / gdim;   // 18 or 19 tiles

    bf16x8 Bf[4][8];   // wave w owns N cols [64w, 64w+64)
#pragma unroll
    for (int nt = 0; nt < 4; ++nt) {
        int n = w * 64 + nt * 16 + l15;
#pragma unroll
        for (int ks = 0; ks < 8; ++ks)
            Bf[nt][ks] = *(const bf16x8*)(w1t + n * 256 + ks * 32 + quad * 8);
    }
    float b1v[4], w2v[4];
#pragma unroll
    for (int nt = 0; nt < 4; ++nt) {
        int n = w * 64 + nt * 16 + l15;
        b1v[nt] = b1[n];
        w2v[nt] = w2[n];
    }
    const float b2v = b2p[0];

    for (int idx = t; idx < J * MT; idx += BLK)
        eld[idx] = edges[(size_t)(bx + (idx >> 5) * gdim) * MT + (idx & 31)];
    __syncthreads();

    const int sm = t >> 3;     // edge row in tile 0..31
    const int sc = t & 7;      // 64B chunk in row

    // single prefetch set; plain named regs (no spill risk).
    uint4 s0, s1, s2, s3, d0, d1, d2, d3;

    auto issue = [&](int j) {
        int2 ed = eld[j * MT + sm];
        const uint4* ps = (const uint4*)(hbf + (size_t)ed.x * DIM) + sc * 4;
        const uint4* pd = (const uint4*)(hbf + (size_t)ed.y * DIM) + sc * 4;
        s0 = ps[0]; s1 = ps[1]; s2 = ps[2]; s3 = ps[3];
        d0 = pd[0]; d1 = pd[1]; d2 = pd[2]; d3 = pd[3];
    };
    auto mul8 = [](uint4 a, uint4 b) -> uint4 {
        union U { uint4 v; __hip_bfloat162 h[4]; } ua, ub, o;
        ua.v = a; ub.v = b;
#pragma unroll
        for (int q = 0; q < 4; ++q) o.h[q] = __hmul2(ua.h[q], ub.h[q]);
        return o.v;
    };
    auto had = [&](int buf) {
        uint4* dst = (uint4*)&xlds[buf][sm][sc * 32];
        dst[0] = mul8(s0, d0);
        dst[1] = mul8(s1, d1);
        dst[2] = mul8(s2, d2);
        dst[3] = mul8(s3, d3);
    };
    auto finalize = [&](int j, int par) {
        if (t < MT) {
            float s = b2v;
#pragma unroll
            for (int ww = 0; ww < 4; ++ww) s += part[par][ww][t];
            out[(size_t)(bx + j * gdim) * MT + t] = s;
        }
    };

    // prologue
    issue(0);
    had(0);                   // xlds[0] <- tile 0 (visible after first barrier)
    if (J > 1) issue(1);

    for (int j = 0; j < J; ++j) {
        const int par = j & 1;
        barrier_lgkm();                   // does NOT drain vmcnt
        if (j > 0) finalize(j - 1, par ^ 1);

        // ---- MFMA on tile j from xlds[par] (overlaps in-flight gathers) ----
        f32x4 acc[2][4];
#pragma unroll
        for (int ms = 0; ms < 2; ++ms)
#pragma unroll
            for (int nt = 0; nt < 4; ++nt)
                acc[ms][nt] = (f32x4){0.f, 0.f, 0.f, 0.f};
        const ushort* xb = &xlds[par][0][0];
#pragma unroll
        for (int ks = 0; ks < 8; ++ks) {
            int kb = ks * 32 + quad * 8;
            bf16x8 a0 = *(const bf16x8*)(xb + l15 * 264 + kb);
            bf16x8 a1 = *(const bf16x8*)(xb + (16 + l15) * 264 + kb);
#pragma unroll
            for (int nt = 0; nt < 4; ++nt) {
                acc[0][nt] = __builtin_amdgcn_mfma_f32_16x16x32_bf16(a0, Bf[nt][ks], acc[0][nt], 0, 0, 0);
                acc[1][nt] = __builtin_amdgcn_mfma_f32_16x16x32_bf16(a1, Bf[nt][ks], acc[1][nt], 0, 0, 0);
            }
        }
        // epilogue: relu(hid+b1).w2, butterfly over 16 n-lanes
        // C/D: row m = ms*16 + quad*4 + r, col n = w*64 + nt*16 + l15
        float red[2][4];
#pragma unroll
        for (int ms = 0; ms < 2; ++ms)
#pragma unroll
            for (int r = 0; r < 4; ++r) {
                float s = 0.f;
#pragma unroll
                for (int nt = 0; nt < 4; ++nt)
                    s += fmaxf(acc[ms][nt][r] + b1v[nt], 0.f) * w2v[nt];
                red[ms][r] = s;
            }
#pragma unroll
        for (int mask = 1; mask <= 8; mask <<= 1)
#pragma unroll
            for (int ms = 0; ms < 2; ++ms)
#pragma unroll
                for (int r = 0; r < 4; ++r)
                    red[ms][r] += __shfl_xor(red[ms][r], mask);
        if (l15 == 0)
#pragma unroll
            for (int ms = 0; ms < 2; ++ms)
#pragma unroll
                for (int r = 0; r < 4; ++r)
                    part[par][w][ms * 16 + quad * 4 + r] = red[ms][r];

        // ---- consume prefetch regs (vmcnt wait lands after MFMA) ----
        if (j + 1 < J) had(par ^ 1);      // xlds[par^1] <- tile j+1
        if (j + 2 < J) issue(j + 2);      // in flight across next barrier
    }

    __syncthreads();
    finalize(J - 1, (J - 1) & 1);
}

// fp32-gather fallback (only if ws too small for hbf; not expected to run)
__global__ __launch_bounds__(512, 4)
void decoder_f32(const float* __restrict__ h, const int2* __restrict__ edges,
                 const ushort* __restrict__ w1t, const float* __restrict__ b1,
                 const float* __restrict__ w2, const float* __restrict__ b2p,
                 float* __restrict__ out) {
    __shared__ ushort xlds[MT][264];
    __shared__ float part[8][MT];
    const int t = threadIdx.x;
    const int w = t >> 6, lane = t & 63, quad = lane >> 4, l15 = lane & 15;
    bf16x8 Bf[2][8];
#pragma unroll
    for (int nt = 0; nt < 2; ++nt)
#pragma unroll
        for (int ks = 0; ks < 8; ++ks)
            Bf[nt][ks] = *(const bf16x8*)(w1t + (w * 32 + nt * 16 + l15) * 256 + ks * 32 + quad * 8);
    float b1v[2], w2v[2];
#pragma unroll
    for (int nt = 0; nt < 2; ++nt) {
        b1v[nt] = b1[w * 32 + nt * 16 + l15];
        w2v[nt] = w2[w * 32 + nt * 16 + l15];
    }
    const float b2v = b2p[0];
    const int sm = t >> 4, sc = t & 15;
    for (int mb = blockIdx.x; mb < NTILES; mb += gridDim.x) {
        int2 ed = edges[mb * MT + sm];
        const float4* ps = (const float4*)(h + (size_t)ed.x * DIM) + sc * 4;
        const float4* pd = (const float4*)(h + (size_t)ed.y * DIM) + sc * 4;
        union { ushort s[16]; uint4 v[2]; } o;
#pragma unroll
        for (int jj = 0; jj < 4; ++jj) {
            float4 a = ps[jj], b = pd[jj];
            o.s[4 * jj + 0] = f2bf(a.x * b.x); o.s[4 * jj + 1] = f2bf(a.y * b.y);
            o.s[4 * jj + 2] = f2bf(a.z * b.z); o.s[4 * jj + 3] = f2bf(a.w * b.w);
        }
        uint4* dst = (uint4*)&xlds[sm][sc * 16];
        dst[0] = o.v[0]; dst[1] = o.v[1];
        __syncthreads();
        f32x4 acc[2][2];
#pragma unroll
        for (int ms = 0; ms < 2; ++ms)
#pragma unroll
            for (int nt = 0; nt < 2; ++nt) acc[ms][nt] = (f32x4){0.f,0.f,0.f,0.f};
#pragma unroll
        for (int ks = 0; ks < 8; ++ks) {
            int kb = ks * 32 + quad * 8;
            bf16x8 a0 = *(const bf16x8*)&xlds[l15][kb];
            bf16x8 a1 = *(const bf16x8*)&xlds[16 + l15][kb];
#pragma unroll
            for (int nt = 0; nt < 2; ++nt) {
                acc[0][nt] = __builtin_amdgcn_mfma_f32_16x16x32_bf16(a0, Bf[nt][ks], acc[0][nt], 0, 0, 0);
                acc[1][nt] = __builtin_amdgcn_mfma_f32_16x16x32_bf16(a1, Bf[nt][ks], acc[1][nt], 0, 0, 0);
            }
        }
        float red[2][4];
#pragma unroll
        for (int ms = 0; ms < 2; ++ms)
#pragma unroll
            for (int r = 0; r < 4; ++r) {
                float s = 0.f;
#pragma unroll
                for (int nt = 0; nt < 2; ++nt)
                    s += fmaxf(acc[ms][nt][r] + b1v[nt], 0.f) * w2v[nt];
                red[ms][r] = s;
            }
#pragma unroll
        for (int mask = 1; mask <= 8; mask <<= 1)
#pragma unroll
            for (int ms = 0; ms < 2; ++ms)
#pragma unroll
                for (int r = 0; r < 4; ++r)
                    red[ms][r] += __shfl_xor(red[ms][r], mask);
        if (l15 == 0)
#pragma unroll
            for (int ms = 0; ms < 2; ++ms)
#pragma unroll
                for (int r = 0; r < 4; ++r)
                    part[w][ms * 16 + quad * 4 + r] = red[ms][r];
        __syncthreads();
        if (t < MT) {
            float s = b2v;
#pragma unroll
            for (int ww = 0; ww < 8; ++ww) s += part[ww][t];
            out[mb * MT + t] = s;
        }
    }
}

extern "C" void kernel_launch(void* const* d_in, const int* in_sizes, int n_in,
                              void* d_out, int out_size, void* d_ws, size_t ws_size,
                              hipStream_t stream) {
    const float* h     = (const float*)d_in[0];
    const int2*  edges = (const int2*)d_in[1];
    const float* W1    = (const float*)d_in[2];
    const float* b1    = (const float*)d_in[3];
    const float* W2    = (const float*)d_in[4];
    const float* b2    = (const float*)d_in[5];
    float* out = (float*)d_out;

    ushort* w1t = (ushort*)d_ws;                     // 128 KB
    ushort* hbf = (ushort*)((char*)d_ws + 131072);   // 51.2 MB

    prep_w1t<<<256, 256, 0, stream>>>(W1, w1t);
    if (ws_size >= 131072 + (size_t)25600000 * 2) {
        prep_hbf<<<12500, 256, 0, stream>>>(h, hbf);
        decoder<<<GRID_MAIN, BLK, 0, stream>>>(hbf, edges, w1t, b1, W2, b2, out);
    } else {
        decoder_f32<<<512, 512, 0, stream>>>(h, edges, w1t, b1, W2, b2, out);
    }
}